// Round 13
// baseline (532.308 us; speedup 1.0000x reference)
//
#include <hip/hip_runtime.h>
#include <hip/hip_bf16.h>

// SwinBlock r13: r12 + mlp2ln2 widened to 128x256 tile (projln1 geometry,
// 1.9x MFMA per staged byte vs 64x256), K=1024 3-deep counted-vmcnt loop.
// All other kernels r12-exact.
// B=32 H=W=56 C=256 NH=8 HD=32 WS=7 SS=3 L=49 nWin=64 -> 2048 windows, M=100352.

typedef unsigned short ushort_t;
typedef short bf16x8 __attribute__((ext_vector_type(8)));
typedef float f32x4 __attribute__((ext_vector_type(4)));

#define WAITV0 asm volatile("s_waitcnt vmcnt(0)" ::: "memory")
#define WAITV3 asm volatile("s_waitcnt vmcnt(3)" ::: "memory")
#define WAITV4 asm volatile("s_waitcnt vmcnt(4)" ::: "memory")
#define WAITL0 asm volatile("s_waitcnt lgkmcnt(0)" ::: "memory")
#define BAR    __builtin_amdgcn_s_barrier()

__device__ __forceinline__ float bf2f(unsigned short u) {
    union { unsigned int i; float f; } x; x.i = ((unsigned int)u) << 16; return x.f;
}
__device__ __forceinline__ unsigned short f2bf(float f) {
    union { float f; unsigned int i; } x; x.f = f;
    unsigned int r = x.i + 0x7fffu + ((x.i >> 16) & 1u);   // RNE
    return (unsigned short)(r >> 16);
}
__device__ __forceinline__ bf16x8 pack8(float4 a, float4 b) {
    bf16x8 r;
    r[0] = (short)f2bf(a.x); r[1] = (short)f2bf(a.y);
    r[2] = (short)f2bf(a.z); r[3] = (short)f2bf(a.w);
    r[4] = (short)f2bf(b.x); r[5] = (short)f2bf(b.y);
    r[6] = (short)f2bf(b.z); r[7] = (short)f2bf(b.w);
    return r;
}
__device__ __forceinline__ void gl_lds16(const ushort_t* g, ushort_t* l) {
    __builtin_amdgcn_global_load_lds((const __attribute__((address_space(1))) void*)g,
                                     (__attribute__((address_space(3))) void*)l, 16, 0, 0);
}
// exact-erf GELU via Abramowitz-Stegun 7.1.26 (max |err| 1.5e-7)
__device__ __forceinline__ float gelu_f(float v) {
    float s = v * 0.70710678118654752f;
    float ax = fabsf(s);
    float t = __builtin_amdgcn_rcpf(1.0f + 0.3275911f * ax);
    float poly = ((((1.061405429f * t - 1.453152027f) * t + 1.421413741f) * t
                   - 0.284496736f) * t + 0.254829592f) * t;
    float y = 1.0f - poly * __expf(-ax * ax);
    float e = (s < 0.f) ? -y : y;
    return 0.5f * v * (1.0f + e);
}

// row m of the windowed/shifted activation -> element offset into x[B,H,W,C]
__device__ __forceinline__ long swin_src_off(int m) {
    int n = m / 49, l = m - n * 49;
    int b = n >> 6, win = n & 63;
    int wh = win >> 3, ww = win & 7;
    int i = l / 7, j = l - i * 7;
    int hs = wh * 7 + i + 3; if (hs >= 56) hs -= 56;   // roll(-3)
    int ws = ww * 7 + j + 3; if (ws >= 56) ws -= 56;
    return ((long)(b * 56 + hs) * 56 + ws) * 256;
}

// ---------------- prep: weights fp32 -> bf16 [N][K] (optional transpose) ----
template<int SRCT>
__global__ __launch_bounds__(256)
void convW(const float* __restrict__ src, ushort_t* __restrict__ dst, int N, int kshift)
{
    int idx = blockIdx.x * 256 + threadIdx.x;
    int kk = idx & ((1 << kshift) - 1), nn = idx >> kshift;
    float v = SRCT ? src[(long)kk * N + nn] : src[idx];
    dst[idx] = f2bf(v);
}

// ---- gemmW: 128x256 tile, 512 thr / 8 waves, BK=32, 3-deep counted-vmcnt loop ----
template<int ACT, int AMODE, int NCOLS>
__global__ __launch_bounds__(512)
void gemmW(const void* __restrict__ Av, const ushort_t* __restrict__ W,
           const float* __restrict__ bias, ushort_t* __restrict__ C,
           int M, int N, int K)
{
    constexpr int NA = (AMODE == 1) ? 2 : 3;
    __shared__ ushort_t As[NA * 4096];
    __shared__ ushort_t Bs[3 * 8192];
    const int t = threadIdx.x, lane = t & 63, w = t >> 6;
    const int cpx = gridDim.x >> 3;
    const int wg = (blockIdx.x & 7) * cpx + (blockIdx.x >> 3);
    const int row0 = (wg / NCOLS) * 128, col0 = (wg % NCOLS) * 256;
    const int wm = (w >> 2) * 64, wn = (w & 3) * 64;

    const int ra = t >> 2, sa = ((t & 3) ^ ((ra >> 1) & 3)) * 8;
    const ushort_t* ag = nullptr;
    const float* axr = nullptr;
    if (AMODE == 0) ag = (const ushort_t*)Av + (long)(row0 + ra) * K + sa;
    else            axr = (const float*)Av + swin_src_off(row0 + ra) + sa;

    const int ub0 = t, ub1 = t + 512;
    const int rb0 = ub0 >> 2, sb0 = ((ub0 & 3) ^ ((rb0 >> 1) & 3)) * 8;
    const int rb1 = ub1 >> 2, sb1 = ((ub1 & 3) ^ ((rb1 >> 1) & 3)) * 8;
    const ushort_t* bg0 = W + (long)(col0 + rb0) * K + sb0;
    const ushort_t* bg1 = W + (long)(col0 + rb1) * K + sb1;

    int offA[4], offB[4];
    #pragma unroll
    for (int i = 0; i < 4; i++) {
        int r2 = wm + i * 16 + (lane & 15);
        offA[i] = r2 * 32 + (((lane >> 4) ^ ((r2 >> 1) & 3)) * 8);
        int r3 = wn + i * 16 + (lane & 15);
        offB[i] = r3 * 32 + (((lane >> 4) ^ ((r3 >> 1) & 3)) * 8);
    }

    f32x4 acc[4][4] = {};
    float4 va0, vb0, va1, vb1;           // AMODE1: A(j) lives in set j&1

    if (AMODE == 0) {
        gl_lds16(ag,      &As[t * 8]);
        gl_lds16(bg0,      &Bs[ub0 * 8]);
        gl_lds16(bg1,      &Bs[ub1 * 8]);
        gl_lds16(ag + 32, &As[4096 + t * 8]);
        gl_lds16(bg0 + 32, &Bs[8192 + ub0 * 8]);
        gl_lds16(bg1 + 32, &Bs[8192 + ub1 * 8]);
        WAITV3; BAR;
    } else {
        va0 = *(const float4*)axr;        vb0 = *(const float4*)(axr + 4);
        gl_lds16(bg0,      &Bs[ub0 * 8]);
        gl_lds16(bg1,      &Bs[ub1 * 8]);
        va1 = *(const float4*)(axr + 32); vb1 = *(const float4*)(axr + 36);
        gl_lds16(bg0 + 32, &Bs[8192 + ub0 * 8]);
        gl_lds16(bg1 + 32, &Bs[8192 + ub1 * 8]);
        WAITV4;
        *(bf16x8*)&As[t * 8] = pack8(va0, vb0);
        WAITL0; BAR;
    }

    const int nk = K >> 5;
    int i0 = 0, i1 = 1, i2 = 2;
    for (int kt = 0; kt < nk; kt++) {
        const bool more = (kt + 2 < nk);
        if (more) {
            const int k2 = (kt + 2) * 32;
            if (AMODE == 0) {
                gl_lds16(ag + k2, &As[i2 * 4096 + t * 8]);
            } else {
                if (kt & 1) { va1 = *(const float4*)(axr + k2); vb1 = *(const float4*)(axr + k2 + 4); }
                else        { va0 = *(const float4*)(axr + k2); vb0 = *(const float4*)(axr + k2 + 4); }
            }
            gl_lds16(bg0 + k2, &Bs[i2 * 8192 + ub0 * 8]);
            gl_lds16(bg1 + k2, &Bs[i2 * 8192 + ub1 * 8]);
        }
        {
            const int abase = (AMODE == 1 ? (kt & 1) : i0) * 4096;
            const int bbase = i0 * 8192;
            bf16x8 af[4], bw[4];
            #pragma unroll
            for (int i = 0; i < 4; i++) {
                af[i] = *(const bf16x8*)&As[abase + offA[i]];
                bw[i] = *(const bf16x8*)&Bs[bbase + offB[i]];
            }
            #pragma unroll
            for (int mi = 0; mi < 4; mi++)
                #pragma unroll
                for (int ni = 0; ni < 4; ni++)
                    acc[mi][ni] = __builtin_amdgcn_mfma_f32_16x16x32_bf16(af[mi], bw[ni], acc[mi][ni], 0, 0, 0);
        }
        if (kt < nk - 1) {
            if (AMODE == 0) {
                if (more) { WAITV3; } else { WAITV0; }
            } else {
                if (more) { WAITV4; } else { WAITV0; }
                if (kt & 1) *(bf16x8*)&As[t * 8]        = pack8(va0, vb0);
                else        *(bf16x8*)&As[4096 + t * 8] = pack8(va1, vb1);
                WAITL0;
            }
            BAR;
        }
        int tmp = i0; i0 = i1; i1 = i2; i2 = tmp;
    }

    #pragma unroll
    for (int mi = 0; mi < 4; mi++)
        #pragma unroll
        for (int ni = 0; ni < 4; ni++) {
            const int c = col0 + wn + ni * 16 + (lane & 15);
            const float bv = bias[c];
            #pragma unroll
            for (int r = 0; r < 4; r++) {
                const int rr = row0 + wm + mi * 16 + (lane >> 4) * 4 + r;
                float v = acc[mi][ni][r] + bv;
                if (ACT) v = gelu_f(v);
                C[(long)rr * N + c] = f2bf(v);
            }
        }
}

// ---------------- MFMA attention: one wave per (window, head) ----------------
__global__ __launch_bounds__(64)
void attn_mfma(const ushort_t* __restrict__ qkv, const float* __restrict__ rpb,
               ushort_t* __restrict__ out)
{
    __shared__ ushort_t v_t[32 * 72];    // V^T [d][j], pad 72
    __shared__ ushort_t p_lds[64 * 72];  // P   [i][j], pad 72
    __shared__ float bias_s[169];

    const int blk = blockIdx.x;
    const int n = blk >> 3, h = blk & 7;
    const int l = threadIdx.x;           // 0..63
    const long wbase = (long)n * 49 * 768 + h * 32;
    const float scale = 0.17677669529663687f;   // 32^-0.5

    {
        int j = min(l, 48);
        const ushort_t* vr = qkv + wbase + (long)j * 768 + 512;
        #pragma unroll
        for (int c = 0; c < 4; c++) {
            bf16x8 vv = *(const bf16x8*)(vr + c * 8);
            #pragma unroll
            for (int e = 0; e < 8; e++) v_t[(c * 8 + e) * 72 + l] = (ushort_t)vv[e];
        }
    }
    for (int idx = l; idx < 169; idx += 64) bias_s[idx] = rpb[idx * 8 + h];
    __syncthreads();

    f32x4 s[4][4] = {};
    {
        bf16x8 aq[4], bk[4];
        #pragma unroll
        for (int mt = 0; mt < 4; mt++) {
            int i = min(mt * 16 + (l & 15), 48);
            aq[mt] = *(const bf16x8*)(qkv + wbase + (long)i * 768 + (l >> 4) * 8);
        }
        #pragma unroll
        for (int nt = 0; nt < 4; nt++) {
            int j = min(nt * 16 + (l & 15), 48);
            bk[nt] = *(const bf16x8*)(qkv + wbase + (long)j * 768 + 256 + (l >> 4) * 8);
        }
        #pragma unroll
        for (int mt = 0; mt < 4; mt++)
            #pragma unroll
            for (int nt = 0; nt < 4; nt++)
                s[mt][nt] = __builtin_amdgcn_mfma_f32_16x16x32_bf16(aq[mt], bk[nt], s[mt][nt], 0, 0, 0);
    }

    const int win = n & 63, wh = win >> 3, ww = win & 7;
    int yj[4], xj[4], regj[4]; bool jv[4];
    #pragma unroll
    for (int nt = 0; nt < 4; nt++) {
        int j = nt * 16 + (l & 15);
        jv[nt] = (j <= 48);
        int jc = min(j, 48);
        yj[nt] = jc / 7; xj[nt] = jc - yj[nt] * 7;
        int hs = wh * 7 + yj[nt], wsx = ww * 7 + xj[nt];
        regj[nt] = (hs < 49 ? 0 : (hs < 53 ? 1 : 2)) * 3 + (wsx < 49 ? 0 : (wsx < 53 ? 1 : 2));
    }
    float rinv[4][4];
    #pragma unroll
    for (int mt = 0; mt < 4; mt++) {
        #pragma unroll
        for (int r = 0; r < 4; r++) {
            int i = mt * 16 + (l >> 4) * 4 + r;
            int ic = min(i, 48);
            int yi = ic / 7, xi = ic - yi * 7;
            int hs = wh * 7 + yi, wsx = ww * 7 + xi;
            int regi = (hs < 49 ? 0 : (hs < 53 ? 1 : 2)) * 3 + (wsx < 49 ? 0 : (wsx < 53 ? 1 : 2));
            float val[4];
            #pragma unroll
            for (int nt = 0; nt < 4; nt++) {
                float v = s[mt][nt][r] * scale + bias_s[(yi - yj[nt] + 6) * 13 + (xi - xj[nt] + 6)];
                if (regi != regj[nt]) v -= 100.f;
                val[nt] = jv[nt] ? v : -1e30f;
            }
            float mx = fmaxf(fmaxf(val[0], val[1]), fmaxf(val[2], val[3]));
            #pragma unroll
            for (int off = 1; off <= 8; off <<= 1) mx = fmaxf(mx, __shfl_xor(mx, off));
            float sum = 0.f;
            #pragma unroll
            for (int nt = 0; nt < 4; nt++) { val[nt] = __expf(val[nt] - mx); sum += val[nt]; }
            #pragma unroll
            for (int off = 1; off <= 8; off <<= 1) sum += __shfl_xor(sum, off);
            rinv[mt][r] = 1.0f / sum;
            #pragma unroll
            for (int nt = 0; nt < 4; nt++)
                p_lds[i * 72 + nt * 16 + (l & 15)] = f2bf(val[nt]);
        }
    }
    __syncthreads();

    f32x4 o[4][2] = {};
    #pragma unroll
    for (int ks = 0; ks < 2; ks++) {
        bf16x8 pa[4], vb[2];
        #pragma unroll
        for (int mt = 0; mt < 4; mt++)
            pa[mt] = *(const bf16x8*)&p_lds[(mt * 16 + (l & 15)) * 72 + ks * 32 + (l >> 4) * 8];
        #pragma unroll
        for (int nt = 0; nt < 2; nt++)
            vb[nt] = *(const bf16x8*)&v_t[(nt * 16 + (l & 15)) * 72 + ks * 32 + (l >> 4) * 8];
        #pragma unroll
        for (int mt = 0; mt < 4; mt++)
            #pragma unroll
            for (int nt = 0; nt < 2; nt++)
                o[mt][nt] = __builtin_amdgcn_mfma_f32_16x16x32_bf16(pa[mt], vb[nt], o[mt][nt], 0, 0, 0);
    }
    #pragma unroll
    for (int mt = 0; mt < 4; mt++)
        #pragma unroll
        for (int r = 0; r < 4; r++) {
            int i = mt * 16 + (l >> 4) * 4 + r;
            if (i < 49) {
                float rs = rinv[mt][r];
                #pragma unroll
                for (int nt = 0; nt < 2; nt++) {
                    int d = nt * 16 + (l & 15);
                    out[((long)n * 49 + i) * 256 + h * 32 + d] = f2bf(o[mt][nt][r] * rs);
                }
            }
        }
}

// ------- projln1: 128x256 3-deep GEMM + LN1 + residual -> x1 bf16 (512 thr) -------
__global__ __launch_bounds__(512)
void projln1(const ushort_t* __restrict__ A, const ushort_t* __restrict__ W,
             const float* __restrict__ pb, const float* __restrict__ x,
             const float* __restrict__ gamma, const float* __restrict__ beta,
             ushort_t* __restrict__ x1b)
{
    __shared__ ushort_t As[3 * 4096];
    __shared__ ushort_t Bs[3 * 8192];
    __shared__ float red_s[128][4];
    __shared__ float red_ss[128][4];
    __shared__ int srow_s[128];
    const int t = threadIdx.x, lane = t & 63, w = t >> 6;
    const int row0 = blockIdx.x * 128;
    const int wm = (w >> 2) * 64, wn = (w & 3) * 64;

    if (t < 128) srow_s[t] = (int)(swin_src_off(row0 + t) >> 8);

    const int ra0 = t >> 2, sa0 = ((t & 3) ^ ((ra0 >> 1) & 3)) * 8;
    const ushort_t* ag = A + (long)(row0 + ra0) * 256 + sa0;
    const int ub0 = t, ub1 = t + 512;
    const int rb0 = ub0 >> 2, sb0 = ((ub0 & 3) ^ ((rb0 >> 1) & 3)) * 8;
    const int rb1 = ub1 >> 2, sb1 = ((ub1 & 3) ^ ((rb1 >> 1) & 3)) * 8;
    const ushort_t* bg0 = W + (long)rb0 * 256 + sb0;
    const ushort_t* bg1 = W + (long)rb1 * 256 + sb1;

    int offA[4], offB[4];
    #pragma unroll
    for (int i = 0; i < 4; i++) {
        int ra = wm + i * 16 + (lane & 15);
        offA[i] = ra * 32 + (((lane >> 4) ^ ((ra >> 1) & 3)) * 8);
        int rb = wn + i * 16 + (lane & 15);
        offB[i] = rb * 32 + (((lane >> 4) ^ ((rb >> 1) & 3)) * 8);
    }

    f32x4 acc[4][4] = {};
    gl_lds16(ag,       &As[t * 8]);
    gl_lds16(bg0,       &Bs[ub0 * 8]);
    gl_lds16(bg1,       &Bs[ub1 * 8]);
    gl_lds16(ag + 32,  &As[4096 + t * 8]);
    gl_lds16(bg0 + 32,  &Bs[8192 + ub0 * 8]);
    gl_lds16(bg1 + 32,  &Bs[8192 + ub1 * 8]);
    WAITV3; BAR;

    int i0 = 0, i1 = 1, i2 = 2;
    for (int kt = 0; kt < 8; kt++) {
        const bool more = (kt + 2 < 8);
        if (more) {
            const int k2 = (kt + 2) * 32;
            gl_lds16(ag + k2, &As[i2 * 4096 + t * 8]);
            gl_lds16(bg0 + k2, &Bs[i2 * 8192 + ub0 * 8]);
            gl_lds16(bg1 + k2, &Bs[i2 * 8192 + ub1 * 8]);
        }
        bf16x8 af[4], bw[4];
        #pragma unroll
        for (int i = 0; i < 4; i++) {
            af[i] = *(const bf16x8*)&As[i0 * 4096 + offA[i]];
            bw[i] = *(const bf16x8*)&Bs[i0 * 8192 + offB[i]];
        }
        #pragma unroll
        for (int mi = 0; mi < 4; mi++)
            #pragma unroll
            for (int ni = 0; ni < 4; ni++)
                acc[mi][ni] = __builtin_amdgcn_mfma_f32_16x16x32_bf16(af[mi], bw[ni], acc[mi][ni], 0, 0, 0);
        if (kt < 7) {
            if (more) { WAITV3; } else { WAITV0; }
            BAR;
        }
        int tmp = i0; i0 = i1; i1 = i2; i2 = tmp;
    }

    float pbv[4], g1v[4], be1v[4];
    #pragma unroll
    for (int ni = 0; ni < 4; ni++) {
        int col = wn + ni * 16 + (lane & 15);
        pbv[ni] = pb[col]; g1v[ni] = gamma[col]; be1v[ni] = beta[col];
    }
    #pragma unroll
    for (int mi = 0; mi < 4; mi++)
        #pragma unroll
        for (int rr = 0; rr < 4; rr++) {
            float s = 0.f, ss = 0.f;
            #pragma unroll
            for (int ni = 0; ni < 4; ni++) {
                float v = acc[mi][ni][rr] + pbv[ni];
                acc[mi][ni][rr] = v; s += v; ss += v * v;
            }
            #pragma unroll
            for (int off = 1; off <= 8; off <<= 1) { s += __shfl_xor(s, off); ss += __shfl_xor(ss, off); }
            if ((lane & 15) == 0) {
                int r = wm + mi * 16 + (lane >> 4) * 4 + rr;
                red_s[r][w & 3] = s; red_ss[r][w & 3] = ss;
            }
        }
    __syncthreads();
    #pragma unroll
    for (int mi = 0; mi < 4; mi++)
        #pragma unroll
        for (int rr = 0; rr < 4; rr++) {
            const int r = wm + mi * 16 + (lane >> 4) * 4 + rr;
            const float s = red_s[r][0] + red_s[r][1] + red_s[r][2] + red_s[r][3];
            const float ss = red_ss[r][0] + red_ss[r][1] + red_ss[r][2] + red_ss[r][3];
            const float mu = s * (1.0f / 256.0f);
            const float rstd = rsqrtf(ss * (1.0f / 256.0f) - mu * mu + 1e-5f);
            const long sp = srow_s[r];
            #pragma unroll
            for (int ni = 0; ni < 4; ni++) {
                int col = wn + ni * 16 + (lane & 15);
                float o = x[sp * 256 + col] + (acc[mi][ni][rr] - mu) * rstd * g1v[ni] + be1v[ni];
                x1b[sp * 256 + col] = f2bf(o);
            }
        }
}

// ------- mlp2ln2: 128x256 3-deep GEMM (K=1024) + LN2 + bf16 residual, fp32 out ----
__global__ __launch_bounds__(512)
void mlp2ln2(const ushort_t* __restrict__ A, const ushort_t* __restrict__ W,
             const float* __restrict__ pb, const ushort_t* __restrict__ x1res,
             const float* __restrict__ gamma, const float* __restrict__ beta,
             float* __restrict__ out)
{
    __shared__ ushort_t As[3 * 4096];
    __shared__ ushort_t Bs[3 * 8192];
    __shared__ float red_s[128][4];
    __shared__ float red_ss[128][4];
    const int t = threadIdx.x, lane = t & 63, w = t >> 6;
    const int row0 = blockIdx.x * 128;
    const int wm = (w >> 2) * 64, wn = (w & 3) * 64;

    const int ra0 = t >> 2, sa0 = ((t & 3) ^ ((ra0 >> 1) & 3)) * 8;
    const ushort_t* ag = A + (long)(row0 + ra0) * 1024 + sa0;
    const int ub0 = t, ub1 = t + 512;
    const int rb0 = ub0 >> 2, sb0 = ((ub0 & 3) ^ ((rb0 >> 1) & 3)) * 8;
    const int rb1 = ub1 >> 2, sb1 = ((ub1 & 3) ^ ((rb1 >> 1) & 3)) * 8;
    const ushort_t* bg0 = W + (long)rb0 * 1024 + sb0;
    const ushort_t* bg1 = W + (long)rb1 * 1024 + sb1;

    int offA[4], offB[4];
    #pragma unroll
    for (int i = 0; i < 4; i++) {
        int ra = wm + i * 16 + (lane & 15);
        offA[i] = ra * 32 + (((lane >> 4) ^ ((ra >> 1) & 3)) * 8);
        int rb = wn + i * 16 + (lane & 15);
        offB[i] = rb * 32 + (((lane >> 4) ^ ((rb >> 1) & 3)) * 8);
    }

    f32x4 acc[4][4] = {};
    gl_lds16(ag,       &As[t * 8]);
    gl_lds16(bg0,       &Bs[ub0 * 8]);
    gl_lds16(bg1,       &Bs[ub1 * 8]);
    gl_lds16(ag + 32,  &As[4096 + t * 8]);
    gl_lds16(bg0 + 32,  &Bs[8192 + ub0 * 8]);
    gl_lds16(bg1 + 32,  &Bs[8192 + ub1 * 8]);
    WAITV3; BAR;

    int i0 = 0, i1 = 1, i2 = 2;
    for (int kt = 0; kt < 32; kt++) {
        const bool more = (kt + 2 < 32);
        if (more) {
            const int k2 = (kt + 2) * 32;
            gl_lds16(ag + k2, &As[i2 * 4096 + t * 8]);
            gl_lds16(bg0 + k2, &Bs[i2 * 8192 + ub0 * 8]);
            gl_lds16(bg1 + k2, &Bs[i2 * 8192 + ub1 * 8]);
        }
        bf16x8 af[4], bw[4];
        #pragma unroll
        for (int i = 0; i < 4; i++) {
            af[i] = *(const bf16x8*)&As[i0 * 4096 + offA[i]];
            bw[i] = *(const bf16x8*)&Bs[i0 * 8192 + offB[i]];
        }
        #pragma unroll
        for (int mi = 0; mi < 4; mi++)
            #pragma unroll
            for (int ni = 0; ni < 4; ni++)
                acc[mi][ni] = __builtin_amdgcn_mfma_f32_16x16x32_bf16(af[mi], bw[ni], acc[mi][ni], 0, 0, 0);
        if (kt < 31) {
            if (more) { WAITV3; } else { WAITV0; }
            BAR;
        }
        int tmp = i0; i0 = i1; i1 = i2; i2 = tmp;
    }

    float pbv[4], g2v[4], be2v[4];
    #pragma unroll
    for (int ni = 0; ni < 4; ni++) {
        int col = wn + ni * 16 + (lane & 15);
        pbv[ni] = pb[col]; g2v[ni] = gamma[col]; be2v[ni] = beta[col];
    }
    #pragma unroll
    for (int mi = 0; mi < 4; mi++)
        #pragma unroll
        for (int rr = 0; rr < 4; rr++) {
            float s = 0.f, ss = 0.f;
            #pragma unroll
            for (int ni = 0; ni < 4; ni++) {
                float v = acc[mi][ni][rr] + pbv[ni];
                acc[mi][ni][rr] = v; s += v; ss += v * v;
            }
            #pragma unroll
            for (int off = 1; off <= 8; off <<= 1) { s += __shfl_xor(s, off); ss += __shfl_xor(ss, off); }
            if ((lane & 15) == 0) {
                int r = wm + mi * 16 + (lane >> 4) * 4 + rr;
                red_s[r][w & 3] = s; red_ss[r][w & 3] = ss;
            }
        }
    __syncthreads();
    #pragma unroll
    for (int mi = 0; mi < 4; mi++)
        #pragma unroll
        for (int rr = 0; rr < 4; rr++) {
            const int r = wm + mi * 16 + (lane >> 4) * 4 + rr;
            const float s = red_s[r][0] + red_s[r][1] + red_s[r][2] + red_s[r][3];
            const float ss = red_ss[r][0] + red_ss[r][1] + red_ss[r][2] + red_ss[r][3];
            const float mu = s * (1.0f / 256.0f);
            const float rstd = rsqrtf(ss * (1.0f / 256.0f) - mu * mu + 1e-5f);
            const long gr = row0 + r;
            #pragma unroll
            for (int ni = 0; ni < 4; ni++) {
                int col = wn + ni * 16 + (lane & 15);
                out[gr * 256 + col] = bf2f(x1res[gr * 256 + col])
                                    + (acc[mi][ni][rr] - mu) * rstd * g2v[ni] + be2v[ni];
            }
        }
}

extern "C" void kernel_launch(void* const* d_in, const int* in_sizes, int n_in,
                              void* d_out, int out_size, void* d_ws, size_t ws_size,
                              hipStream_t stream) {
    const float* x      = (const float*)d_in[0];
    const float* qkv_w  = (const float*)d_in[1];
    const float* qkv_b  = (const float*)d_in[2];
    const float* proj_w = (const float*)d_in[3];
    const float* proj_b = (const float*)d_in[4];
    const float* rpb    = (const float*)d_in[5];
    const float* gamma1 = (const float*)d_in[6];
    const float* beta1  = (const float*)d_in[7];
    const float* w1     = (const float*)d_in[8];
    const float* b1     = (const float*)d_in[9];
    const float* w2     = (const float*)d_in[10];
    const float* b2     = (const float*)d_in[11];
    const float* gamma2 = (const float*)d_in[12];
    const float* beta2  = (const float*)d_in[13];
    float* outf = (float*)d_out;

    // d_out[0,51.4M) holds attnout (bf16) until projln1 consumes it.
    ushort_t* attnout = (ushort_t*)d_out;

    char* ws = (char*)d_ws;
    ushort_t* qkvb  = (ushort_t*)ws;                      // [0,154.1M)  qkv -> attn (dead after)
    ushort_t* hbuf  = (ushort_t*)ws;                      // [0,102.8M)  per-MLP-chunk hidden
    ushort_t* x1b   = (ushort_t*)(ws + 154140672ULL);     // [154.1,205.5M)
    ushort_t* wqkvb = (ushort_t*)(ws + 205520896ULL);     // bf16 weights [N][K]
    ushort_t* wprojb= (ushort_t*)(ws + 205914112ULL);
    ushort_t* w1t   = (ushort_t*)(ws + 206045184ULL);
    ushort_t* w2t   = (ushort_t*)(ws + 206569472ULL);

    const int M = 100352, MC = 50176;   // 2 MLP chunks
    dim3 blk(256);
    // prep: bf16 weights
    convW<0><<<dim3(768),  blk, 0, stream>>>(qkv_w,  wqkvb,  768,  8);   // [768][256]
    convW<0><<<dim3(256),  blk, 0, stream>>>(proj_w, wprojb, 256,  8);   // [256][256]
    convW<1><<<dim3(1024), blk, 0, stream>>>(w1,     w1t,    1024, 8);   // -> [1024][256]
    convW<1><<<dim3(1024), blk, 0, stream>>>(w2,     w2t,    256, 10);   // -> [256][1024]
    // 1. qkv = gather(x) @ Wqkv^T + b  (128x256 tile, fused gather, NCOLS=3)
    gemmW<0, 1, 3><<<dim3(2352), dim3(512), 0, stream>>>(x, wqkvb, qkv_b, qkvb, M, 768, 256);
    // 2. windowed attention
    attn_mfma<<<dim3(16384), dim3(64), 0, stream>>>(qkvb, rpb, attnout);
    // 3. proj + LN1 + residual -> x1 bf16 (scattered to natural row order)
    projln1<<<dim3(784), dim3(512), 0, stream>>>(attnout, wprojb, proj_b, x,
                                                 gamma1, beta1, x1b);
    // 4/5. MLP in 2 M-chunks; h chunk (102.8MB) lives in dead qkvb region
    for (int c2 = 0; c2 < 2; c2++) {
        const long off = (long)c2 * MC * 256;
        gemmW<1, 0, 4><<<dim3(1568), dim3(512), 0, stream>>>(x1b + off, w1t, b1, hbuf, MC, 1024, 256);
        mlp2ln2<<<dim3(392), dim3(512), 0, stream>>>(hbuf, w2t, b2, x1b + off,
                                                     gamma2, beta2, outf + off);
    }
}

// Round 14
// 520.083 us; speedup vs baseline: 1.0235x; 1.0235x over previous
//
#include <hip/hip_runtime.h>
#include <hip/hip_bf16.h>

// SwinBlock r14: r13 + (1) T5 s_setprio(1) around MFMA clusters in all GEMMs,
// (2) MLP merged to full-M single dispatches (hbuf 205.5MB in ws, x1b relocated).
// B=32 H=W=56 C=256 NH=8 HD=32 WS=7 SS=3 L=49 nWin=64 -> 2048 windows, M=100352.

typedef unsigned short ushort_t;
typedef short bf16x8 __attribute__((ext_vector_type(8)));
typedef float f32x4 __attribute__((ext_vector_type(4)));

#define WAITV0 asm volatile("s_waitcnt vmcnt(0)" ::: "memory")
#define WAITV3 asm volatile("s_waitcnt vmcnt(3)" ::: "memory")
#define WAITV4 asm volatile("s_waitcnt vmcnt(4)" ::: "memory")
#define WAITL0 asm volatile("s_waitcnt lgkmcnt(0)" ::: "memory")
#define BAR    __builtin_amdgcn_s_barrier()
#define PRIO1  __builtin_amdgcn_s_setprio(1)
#define PRIO0  __builtin_amdgcn_s_setprio(0)

__device__ __forceinline__ float bf2f(unsigned short u) {
    union { unsigned int i; float f; } x; x.i = ((unsigned int)u) << 16; return x.f;
}
__device__ __forceinline__ unsigned short f2bf(float f) {
    union { float f; unsigned int i; } x; x.f = f;
    unsigned int r = x.i + 0x7fffu + ((x.i >> 16) & 1u);   // RNE
    return (unsigned short)(r >> 16);
}
__device__ __forceinline__ bf16x8 pack8(float4 a, float4 b) {
    bf16x8 r;
    r[0] = (short)f2bf(a.x); r[1] = (short)f2bf(a.y);
    r[2] = (short)f2bf(a.z); r[3] = (short)f2bf(a.w);
    r[4] = (short)f2bf(b.x); r[5] = (short)f2bf(b.y);
    r[6] = (short)f2bf(b.z); r[7] = (short)f2bf(b.w);
    return r;
}
__device__ __forceinline__ void gl_lds16(const ushort_t* g, ushort_t* l) {
    __builtin_amdgcn_global_load_lds((const __attribute__((address_space(1))) void*)g,
                                     (__attribute__((address_space(3))) void*)l, 16, 0, 0);
}
// exact-erf GELU via Abramowitz-Stegun 7.1.26 (max |err| 1.5e-7)
__device__ __forceinline__ float gelu_f(float v) {
    float s = v * 0.70710678118654752f;
    float ax = fabsf(s);
    float t = __builtin_amdgcn_rcpf(1.0f + 0.3275911f * ax);
    float poly = ((((1.061405429f * t - 1.453152027f) * t + 1.421413741f) * t
                   - 0.284496736f) * t + 0.254829592f) * t;
    float y = 1.0f - poly * __expf(-ax * ax);
    float e = (s < 0.f) ? -y : y;
    return 0.5f * v * (1.0f + e);
}

// row m of the windowed/shifted activation -> element offset into x[B,H,W,C]
__device__ __forceinline__ long swin_src_off(int m) {
    int n = m / 49, l = m - n * 49;
    int b = n >> 6, win = n & 63;
    int wh = win >> 3, ww = win & 7;
    int i = l / 7, j = l - i * 7;
    int hs = wh * 7 + i + 3; if (hs >= 56) hs -= 56;   // roll(-3)
    int ws = ww * 7 + j + 3; if (ws >= 56) ws -= 56;
    return ((long)(b * 56 + hs) * 56 + ws) * 256;
}

// ---------------- prep: weights fp32 -> bf16 [N][K] (optional transpose) ----
template<int SRCT>
__global__ __launch_bounds__(256)
void convW(const float* __restrict__ src, ushort_t* __restrict__ dst, int N, int kshift)
{
    int idx = blockIdx.x * 256 + threadIdx.x;
    int kk = idx & ((1 << kshift) - 1), nn = idx >> kshift;
    float v = SRCT ? src[(long)kk * N + nn] : src[idx];
    dst[idx] = f2bf(v);
}

// ---- gemmW: 128x256 tile, 512 thr / 8 waves, BK=32, 3-deep counted-vmcnt loop ----
template<int ACT, int AMODE, int NCOLS>
__global__ __launch_bounds__(512)
void gemmW(const void* __restrict__ Av, const ushort_t* __restrict__ W,
           const float* __restrict__ bias, ushort_t* __restrict__ C,
           int M, int N, int K)
{
    constexpr int NA = (AMODE == 1) ? 2 : 3;
    __shared__ ushort_t As[NA * 4096];
    __shared__ ushort_t Bs[3 * 8192];
    const int t = threadIdx.x, lane = t & 63, w = t >> 6;
    const int cpx = gridDim.x >> 3;
    const int wg = (blockIdx.x & 7) * cpx + (blockIdx.x >> 3);
    const int row0 = (wg / NCOLS) * 128, col0 = (wg % NCOLS) * 256;
    const int wm = (w >> 2) * 64, wn = (w & 3) * 64;

    const int ra = t >> 2, sa = ((t & 3) ^ ((ra >> 1) & 3)) * 8;
    const ushort_t* ag = nullptr;
    const float* axr = nullptr;
    if (AMODE == 0) ag = (const ushort_t*)Av + (long)(row0 + ra) * K + sa;
    else            axr = (const float*)Av + swin_src_off(row0 + ra) + sa;

    const int ub0 = t, ub1 = t + 512;
    const int rb0 = ub0 >> 2, sb0 = ((ub0 & 3) ^ ((rb0 >> 1) & 3)) * 8;
    const int rb1 = ub1 >> 2, sb1 = ((ub1 & 3) ^ ((rb1 >> 1) & 3)) * 8;
    const ushort_t* bg0 = W + (long)(col0 + rb0) * K + sb0;
    const ushort_t* bg1 = W + (long)(col0 + rb1) * K + sb1;

    int offA[4], offB[4];
    #pragma unroll
    for (int i = 0; i < 4; i++) {
        int r2 = wm + i * 16 + (lane & 15);
        offA[i] = r2 * 32 + (((lane >> 4) ^ ((r2 >> 1) & 3)) * 8);
        int r3 = wn + i * 16 + (lane & 15);
        offB[i] = r3 * 32 + (((lane >> 4) ^ ((r3 >> 1) & 3)) * 8);
    }

    f32x4 acc[4][4] = {};
    float4 va0, vb0, va1, vb1;           // AMODE1: A(j) lives in set j&1

    if (AMODE == 0) {
        gl_lds16(ag,      &As[t * 8]);
        gl_lds16(bg0,      &Bs[ub0 * 8]);
        gl_lds16(bg1,      &Bs[ub1 * 8]);
        gl_lds16(ag + 32, &As[4096 + t * 8]);
        gl_lds16(bg0 + 32, &Bs[8192 + ub0 * 8]);
        gl_lds16(bg1 + 32, &Bs[8192 + ub1 * 8]);
        WAITV3; BAR;
    } else {
        va0 = *(const float4*)axr;        vb0 = *(const float4*)(axr + 4);
        gl_lds16(bg0,      &Bs[ub0 * 8]);
        gl_lds16(bg1,      &Bs[ub1 * 8]);
        va1 = *(const float4*)(axr + 32); vb1 = *(const float4*)(axr + 36);
        gl_lds16(bg0 + 32, &Bs[8192 + ub0 * 8]);
        gl_lds16(bg1 + 32, &Bs[8192 + ub1 * 8]);
        WAITV4;
        *(bf16x8*)&As[t * 8] = pack8(va0, vb0);
        WAITL0; BAR;
    }

    const int nk = K >> 5;
    int i0 = 0, i1 = 1, i2 = 2;
    for (int kt = 0; kt < nk; kt++) {
        const bool more = (kt + 2 < nk);
        if (more) {
            const int k2 = (kt + 2) * 32;
            if (AMODE == 0) {
                gl_lds16(ag + k2, &As[i2 * 4096 + t * 8]);
            } else {
                if (kt & 1) { va1 = *(const float4*)(axr + k2); vb1 = *(const float4*)(axr + k2 + 4); }
                else        { va0 = *(const float4*)(axr + k2); vb0 = *(const float4*)(axr + k2 + 4); }
            }
            gl_lds16(bg0 + k2, &Bs[i2 * 8192 + ub0 * 8]);
            gl_lds16(bg1 + k2, &Bs[i2 * 8192 + ub1 * 8]);
        }
        {
            const int abase = (AMODE == 1 ? (kt & 1) : i0) * 4096;
            const int bbase = i0 * 8192;
            bf16x8 af[4], bw[4];
            #pragma unroll
            for (int i = 0; i < 4; i++) {
                af[i] = *(const bf16x8*)&As[abase + offA[i]];
                bw[i] = *(const bf16x8*)&Bs[bbase + offB[i]];
            }
            PRIO1;
            #pragma unroll
            for (int mi = 0; mi < 4; mi++)
                #pragma unroll
                for (int ni = 0; ni < 4; ni++)
                    acc[mi][ni] = __builtin_amdgcn_mfma_f32_16x16x32_bf16(af[mi], bw[ni], acc[mi][ni], 0, 0, 0);
            PRIO0;
        }
        if (kt < nk - 1) {
            if (AMODE == 0) {
                if (more) { WAITV3; } else { WAITV0; }
            } else {
                if (more) { WAITV4; } else { WAITV0; }
                if (kt & 1) *(bf16x8*)&As[t * 8]        = pack8(va0, vb0);
                else        *(bf16x8*)&As[4096 + t * 8] = pack8(va1, vb1);
                WAITL0;
            }
            BAR;
        }
        int tmp = i0; i0 = i1; i1 = i2; i2 = tmp;
    }

    #pragma unroll
    for (int mi = 0; mi < 4; mi++)
        #pragma unroll
        for (int ni = 0; ni < 4; ni++) {
            const int c = col0 + wn + ni * 16 + (lane & 15);
            const float bv = bias[c];
            #pragma unroll
            for (int r = 0; r < 4; r++) {
                const int rr = row0 + wm + mi * 16 + (lane >> 4) * 4 + r;
                float v = acc[mi][ni][r] + bv;
                if (ACT) v = gelu_f(v);
                C[(long)rr * N + c] = f2bf(v);
            }
        }
}

// ---------------- MFMA attention: one wave per (window, head) ----------------
__global__ __launch_bounds__(64)
void attn_mfma(const ushort_t* __restrict__ qkv, const float* __restrict__ rpb,
               ushort_t* __restrict__ out)
{
    __shared__ ushort_t v_t[32 * 72];    // V^T [d][j], pad 72
    __shared__ ushort_t p_lds[64 * 72];  // P   [i][j], pad 72
    __shared__ float bias_s[169];

    const int blk = blockIdx.x;
    const int n = blk >> 3, h = blk & 7;
    const int l = threadIdx.x;           // 0..63
    const long wbase = (long)n * 49 * 768 + h * 32;
    const float scale = 0.17677669529663687f;   // 32^-0.5

    {
        int j = min(l, 48);
        const ushort_t* vr = qkv + wbase + (long)j * 768 + 512;
        #pragma unroll
        for (int c = 0; c < 4; c++) {
            bf16x8 vv = *(const bf16x8*)(vr + c * 8);
            #pragma unroll
            for (int e = 0; e < 8; e++) v_t[(c * 8 + e) * 72 + l] = (ushort_t)vv[e];
        }
    }
    for (int idx = l; idx < 169; idx += 64) bias_s[idx] = rpb[idx * 8 + h];
    __syncthreads();

    f32x4 s[4][4] = {};
    {
        bf16x8 aq[4], bk[4];
        #pragma unroll
        for (int mt = 0; mt < 4; mt++) {
            int i = min(mt * 16 + (l & 15), 48);
            aq[mt] = *(const bf16x8*)(qkv + wbase + (long)i * 768 + (l >> 4) * 8);
        }
        #pragma unroll
        for (int nt = 0; nt < 4; nt++) {
            int j = min(nt * 16 + (l & 15), 48);
            bk[nt] = *(const bf16x8*)(qkv + wbase + (long)j * 768 + 256 + (l >> 4) * 8);
        }
        #pragma unroll
        for (int mt = 0; mt < 4; mt++)
            #pragma unroll
            for (int nt = 0; nt < 4; nt++)
                s[mt][nt] = __builtin_amdgcn_mfma_f32_16x16x32_bf16(aq[mt], bk[nt], s[mt][nt], 0, 0, 0);
    }

    const int win = n & 63, wh = win >> 3, ww = win & 7;
    int yj[4], xj[4], regj[4]; bool jv[4];
    #pragma unroll
    for (int nt = 0; nt < 4; nt++) {
        int j = nt * 16 + (l & 15);
        jv[nt] = (j <= 48);
        int jc = min(j, 48);
        yj[nt] = jc / 7; xj[nt] = jc - yj[nt] * 7;
        int hs = wh * 7 + yj[nt], wsx = ww * 7 + xj[nt];
        regj[nt] = (hs < 49 ? 0 : (hs < 53 ? 1 : 2)) * 3 + (wsx < 49 ? 0 : (wsx < 53 ? 1 : 2));
    }
    float rinv[4][4];
    #pragma unroll
    for (int mt = 0; mt < 4; mt++) {
        #pragma unroll
        for (int r = 0; r < 4; r++) {
            int i = mt * 16 + (l >> 4) * 4 + r;
            int ic = min(i, 48);
            int yi = ic / 7, xi = ic - yi * 7;
            int hs = wh * 7 + yi, wsx = ww * 7 + xi;
            int regi = (hs < 49 ? 0 : (hs < 53 ? 1 : 2)) * 3 + (wsx < 49 ? 0 : (wsx < 53 ? 1 : 2));
            float val[4];
            #pragma unroll
            for (int nt = 0; nt < 4; nt++) {
                float v = s[mt][nt][r] * scale + bias_s[(yi - yj[nt] + 6) * 13 + (xi - xj[nt] + 6)];
                if (regi != regj[nt]) v -= 100.f;
                val[nt] = jv[nt] ? v : -1e30f;
            }
            float mx = fmaxf(fmaxf(val[0], val[1]), fmaxf(val[2], val[3]));
            #pragma unroll
            for (int off = 1; off <= 8; off <<= 1) mx = fmaxf(mx, __shfl_xor(mx, off));
            float sum = 0.f;
            #pragma unroll
            for (int nt = 0; nt < 4; nt++) { val[nt] = __expf(val[nt] - mx); sum += val[nt]; }
            #pragma unroll
            for (int off = 1; off <= 8; off <<= 1) sum += __shfl_xor(sum, off);
            rinv[mt][r] = 1.0f / sum;
            #pragma unroll
            for (int nt = 0; nt < 4; nt++)
                p_lds[i * 72 + nt * 16 + (l & 15)] = f2bf(val[nt]);
        }
    }
    __syncthreads();

    f32x4 o[4][2] = {};
    #pragma unroll
    for (int ks = 0; ks < 2; ks++) {
        bf16x8 pa[4], vb[2];
        #pragma unroll
        for (int mt = 0; mt < 4; mt++)
            pa[mt] = *(const bf16x8*)&p_lds[(mt * 16 + (l & 15)) * 72 + ks * 32 + (l >> 4) * 8];
        #pragma unroll
        for (int nt = 0; nt < 2; nt++)
            vb[nt] = *(const bf16x8*)&v_t[(nt * 16 + (l & 15)) * 72 + ks * 32 + (l >> 4) * 8];
        #pragma unroll
        for (int mt = 0; mt < 4; mt++)
            #pragma unroll
            for (int nt = 0; nt < 2; nt++)
                o[mt][nt] = __builtin_amdgcn_mfma_f32_16x16x32_bf16(pa[mt], vb[nt], o[mt][nt], 0, 0, 0);
    }
    #pragma unroll
    for (int mt = 0; mt < 4; mt++)
        #pragma unroll
        for (int r = 0; r < 4; r++) {
            int i = mt * 16 + (l >> 4) * 4 + r;
            if (i < 49) {
                float rs = rinv[mt][r];
                #pragma unroll
                for (int nt = 0; nt < 2; nt++) {
                    int d = nt * 16 + (l & 15);
                    out[((long)n * 49 + i) * 256 + h * 32 + d] = f2bf(o[mt][nt][r] * rs);
                }
            }
        }
}

// ------- projln1: 128x256 3-deep GEMM + LN1 + residual -> x1 bf16 (512 thr) -------
__global__ __launch_bounds__(512)
void projln1(const ushort_t* __restrict__ A, const ushort_t* __restrict__ W,
             const float* __restrict__ pb, const float* __restrict__ x,
             const float* __restrict__ gamma, const float* __restrict__ beta,
             ushort_t* __restrict__ x1b)
{
    __shared__ ushort_t As[3 * 4096];
    __shared__ ushort_t Bs[3 * 8192];
    __shared__ float red_s[128][4];
    __shared__ float red_ss[128][4];
    __shared__ int srow_s[128];
    const int t = threadIdx.x, lane = t & 63, w = t >> 6;
    const int row0 = blockIdx.x * 128;
    const int wm = (w >> 2) * 64, wn = (w & 3) * 64;

    if (t < 128) srow_s[t] = (int)(swin_src_off(row0 + t) >> 8);

    const int ra0 = t >> 2, sa0 = ((t & 3) ^ ((ra0 >> 1) & 3)) * 8;
    const ushort_t* ag = A + (long)(row0 + ra0) * 256 + sa0;
    const int ub0 = t, ub1 = t + 512;
    const int rb0 = ub0 >> 2, sb0 = ((ub0 & 3) ^ ((rb0 >> 1) & 3)) * 8;
    const int rb1 = ub1 >> 2, sb1 = ((ub1 & 3) ^ ((rb1 >> 1) & 3)) * 8;
    const ushort_t* bg0 = W + (long)rb0 * 256 + sb0;
    const ushort_t* bg1 = W + (long)rb1 * 256 + sb1;

    int offA[4], offB[4];
    #pragma unroll
    for (int i = 0; i < 4; i++) {
        int ra = wm + i * 16 + (lane & 15);
        offA[i] = ra * 32 + (((lane >> 4) ^ ((ra >> 1) & 3)) * 8);
        int rb = wn + i * 16 + (lane & 15);
        offB[i] = rb * 32 + (((lane >> 4) ^ ((rb >> 1) & 3)) * 8);
    }

    f32x4 acc[4][4] = {};
    gl_lds16(ag,       &As[t * 8]);
    gl_lds16(bg0,       &Bs[ub0 * 8]);
    gl_lds16(bg1,       &Bs[ub1 * 8]);
    gl_lds16(ag + 32,  &As[4096 + t * 8]);
    gl_lds16(bg0 + 32,  &Bs[8192 + ub0 * 8]);
    gl_lds16(bg1 + 32,  &Bs[8192 + ub1 * 8]);
    WAITV3; BAR;

    int i0 = 0, i1 = 1, i2 = 2;
    for (int kt = 0; kt < 8; kt++) {
        const bool more = (kt + 2 < 8);
        if (more) {
            const int k2 = (kt + 2) * 32;
            gl_lds16(ag + k2, &As[i2 * 4096 + t * 8]);
            gl_lds16(bg0 + k2, &Bs[i2 * 8192 + ub0 * 8]);
            gl_lds16(bg1 + k2, &Bs[i2 * 8192 + ub1 * 8]);
        }
        bf16x8 af[4], bw[4];
        #pragma unroll
        for (int i = 0; i < 4; i++) {
            af[i] = *(const bf16x8*)&As[i0 * 4096 + offA[i]];
            bw[i] = *(const bf16x8*)&Bs[i0 * 8192 + offB[i]];
        }
        PRIO1;
        #pragma unroll
        for (int mi = 0; mi < 4; mi++)
            #pragma unroll
            for (int ni = 0; ni < 4; ni++)
                acc[mi][ni] = __builtin_amdgcn_mfma_f32_16x16x32_bf16(af[mi], bw[ni], acc[mi][ni], 0, 0, 0);
        PRIO0;
        if (kt < 7) {
            if (more) { WAITV3; } else { WAITV0; }
            BAR;
        }
        int tmp = i0; i0 = i1; i1 = i2; i2 = tmp;
    }

    float pbv[4], g1v[4], be1v[4];
    #pragma unroll
    for (int ni = 0; ni < 4; ni++) {
        int col = wn + ni * 16 + (lane & 15);
        pbv[ni] = pb[col]; g1v[ni] = gamma[col]; be1v[ni] = beta[col];
    }
    #pragma unroll
    for (int mi = 0; mi < 4; mi++)
        #pragma unroll
        for (int rr = 0; rr < 4; rr++) {
            float s = 0.f, ss = 0.f;
            #pragma unroll
            for (int ni = 0; ni < 4; ni++) {
                float v = acc[mi][ni][rr] + pbv[ni];
                acc[mi][ni][rr] = v; s += v; ss += v * v;
            }
            #pragma unroll
            for (int off = 1; off <= 8; off <<= 1) { s += __shfl_xor(s, off); ss += __shfl_xor(ss, off); }
            if ((lane & 15) == 0) {
                int r = wm + mi * 16 + (lane >> 4) * 4 + rr;
                red_s[r][w & 3] = s; red_ss[r][w & 3] = ss;
            }
        }
    __syncthreads();
    #pragma unroll
    for (int mi = 0; mi < 4; mi++)
        #pragma unroll
        for (int rr = 0; rr < 4; rr++) {
            const int r = wm + mi * 16 + (lane >> 4) * 4 + rr;
            const float s = red_s[r][0] + red_s[r][1] + red_s[r][2] + red_s[r][3];
            const float ss = red_ss[r][0] + red_ss[r][1] + red_ss[r][2] + red_ss[r][3];
            const float mu = s * (1.0f / 256.0f);
            const float rstd = rsqrtf(ss * (1.0f / 256.0f) - mu * mu + 1e-5f);
            const long sp = srow_s[r];
            #pragma unroll
            for (int ni = 0; ni < 4; ni++) {
                int col = wn + ni * 16 + (lane & 15);
                float o = x[sp * 256 + col] + (acc[mi][ni][rr] - mu) * rstd * g1v[ni] + be1v[ni];
                x1b[sp * 256 + col] = f2bf(o);
            }
        }
}

// ------- mlp2ln2: 128x256 3-deep GEMM (K=1024) + LN2 + bf16 residual, fp32 out ----
__global__ __launch_bounds__(512)
void mlp2ln2(const ushort_t* __restrict__ A, const ushort_t* __restrict__ W,
             const float* __restrict__ pb, const ushort_t* __restrict__ x1res,
             const float* __restrict__ gamma, const float* __restrict__ beta,
             float* __restrict__ out)
{
    __shared__ ushort_t As[3 * 4096];
    __shared__ ushort_t Bs[3 * 8192];
    __shared__ float red_s[128][4];
    __shared__ float red_ss[128][4];
    const int t = threadIdx.x, lane = t & 63, w = t >> 6;
    const int row0 = blockIdx.x * 128;
    const int wm = (w >> 2) * 64, wn = (w & 3) * 64;

    const int ra0 = t >> 2, sa0 = ((t & 3) ^ ((ra0 >> 1) & 3)) * 8;
    const ushort_t* ag = A + (long)(row0 + ra0) * 1024 + sa0;
    const int ub0 = t, ub1 = t + 512;
    const int rb0 = ub0 >> 2, sb0 = ((ub0 & 3) ^ ((rb0 >> 1) & 3)) * 8;
    const int rb1 = ub1 >> 2, sb1 = ((ub1 & 3) ^ ((rb1 >> 1) & 3)) * 8;
    const ushort_t* bg0 = W + (long)rb0 * 1024 + sb0;
    const ushort_t* bg1 = W + (long)rb1 * 1024 + sb1;

    int offA[4], offB[4];
    #pragma unroll
    for (int i = 0; i < 4; i++) {
        int ra = wm + i * 16 + (lane & 15);
        offA[i] = ra * 32 + (((lane >> 4) ^ ((ra >> 1) & 3)) * 8);
        int rb = wn + i * 16 + (lane & 15);
        offB[i] = rb * 32 + (((lane >> 4) ^ ((rb >> 1) & 3)) * 8);
    }

    f32x4 acc[4][4] = {};
    gl_lds16(ag,       &As[t * 8]);
    gl_lds16(bg0,       &Bs[ub0 * 8]);
    gl_lds16(bg1,       &Bs[ub1 * 8]);
    gl_lds16(ag + 32,  &As[4096 + t * 8]);
    gl_lds16(bg0 + 32,  &Bs[8192 + ub0 * 8]);
    gl_lds16(bg1 + 32,  &Bs[8192 + ub1 * 8]);
    WAITV3; BAR;

    int i0 = 0, i1 = 1, i2 = 2;
    for (int kt = 0; kt < 32; kt++) {
        const bool more = (kt + 2 < 32);
        if (more) {
            const int k2 = (kt + 2) * 32;
            gl_lds16(ag + k2, &As[i2 * 4096 + t * 8]);
            gl_lds16(bg0 + k2, &Bs[i2 * 8192 + ub0 * 8]);
            gl_lds16(bg1 + k2, &Bs[i2 * 8192 + ub1 * 8]);
        }
        bf16x8 af[4], bw[4];
        #pragma unroll
        for (int i = 0; i < 4; i++) {
            af[i] = *(const bf16x8*)&As[i0 * 4096 + offA[i]];
            bw[i] = *(const bf16x8*)&Bs[i0 * 8192 + offB[i]];
        }
        PRIO1;
        #pragma unroll
        for (int mi = 0; mi < 4; mi++)
            #pragma unroll
            for (int ni = 0; ni < 4; ni++)
                acc[mi][ni] = __builtin_amdgcn_mfma_f32_16x16x32_bf16(af[mi], bw[ni], acc[mi][ni], 0, 0, 0);
        PRIO0;
        if (kt < 31) {
            if (more) { WAITV3; } else { WAITV0; }
            BAR;
        }
        int tmp = i0; i0 = i1; i1 = i2; i2 = tmp;
    }

    float pbv[4], g2v[4], be2v[4];
    #pragma unroll
    for (int ni = 0; ni < 4; ni++) {
        int col = wn + ni * 16 + (lane & 15);
        pbv[ni] = pb[col]; g2v[ni] = gamma[col]; be2v[ni] = beta[col];
    }
    #pragma unroll
    for (int mi = 0; mi < 4; mi++)
        #pragma unroll
        for (int rr = 0; rr < 4; rr++) {
            float s = 0.f, ss = 0.f;
            #pragma unroll
            for (int ni = 0; ni < 4; ni++) {
                float v = acc[mi][ni][rr] + pbv[ni];
                acc[mi][ni][rr] = v; s += v; ss += v * v;
            }
            #pragma unroll
            for (int off = 1; off <= 8; off <<= 1) { s += __shfl_xor(s, off); ss += __shfl_xor(ss, off); }
            if ((lane & 15) == 0) {
                int r = wm + mi * 16 + (lane >> 4) * 4 + rr;
                red_s[r][w & 3] = s; red_ss[r][w & 3] = ss;
            }
        }
    __syncthreads();
    #pragma unroll
    for (int mi = 0; mi < 4; mi++)
        #pragma unroll
        for (int rr = 0; rr < 4; rr++) {
            const int r = wm + mi * 16 + (lane >> 4) * 4 + rr;
            const float s = red_s[r][0] + red_s[r][1] + red_s[r][2] + red_s[r][3];
            const float ss = red_ss[r][0] + red_ss[r][1] + red_ss[r][2] + red_ss[r][3];
            const float mu = s * (1.0f / 256.0f);
            const float rstd = rsqrtf(ss * (1.0f / 256.0f) - mu * mu + 1e-5f);
            const long gr = row0 + r;
            #pragma unroll
            for (int ni = 0; ni < 4; ni++) {
                int col = wn + ni * 16 + (lane & 15);
                out[gr * 256 + col] = bf2f(x1res[gr * 256 + col])
                                    + (acc[mi][ni][rr] - mu) * rstd * g2v[ni] + be2v[ni];
            }
        }
}

extern "C" void kernel_launch(void* const* d_in, const int* in_sizes, int n_in,
                              void* d_out, int out_size, void* d_ws, size_t ws_size,
                              hipStream_t stream) {
    const float* x      = (const float*)d_in[0];
    const float* qkv_w  = (const float*)d_in[1];
    const float* qkv_b  = (const float*)d_in[2];
    const float* proj_w = (const float*)d_in[3];
    const float* proj_b = (const float*)d_in[4];
    const float* rpb    = (const float*)d_in[5];
    const float* gamma1 = (const float*)d_in[6];
    const float* beta1  = (const float*)d_in[7];
    const float* w1     = (const float*)d_in[8];
    const float* b1     = (const float*)d_in[9];
    const float* w2     = (const float*)d_in[10];
    const float* b2     = (const float*)d_in[11];
    const float* gamma2 = (const float*)d_in[12];
    const float* beta2  = (const float*)d_in[13];
    float* outf = (float*)d_out;

    // d_out[0,51.4M) holds attnout (bf16) until projln1 consumes it.
    ushort_t* attnout = (ushort_t*)d_out;

    char* ws = (char*)d_ws;
    ushort_t* qkvb  = (ushort_t*)ws;                      // [0,154.1M)   qkv -> attn (dead after)
    ushort_t* x1b   = (ushort_t*)ws;                      // [0,51.4M)    projln1 -> MLP (qkvb dead)
    ushort_t* hbuf  = (ushort_t*)(ws + 51380224ULL);      // [51.4,256.9M) full-M hidden
    ushort_t* wqkvb = (ushort_t*)(ws + 256901120ULL);     // bf16 weights [N][K]
    ushort_t* wprojb= (ushort_t*)(ws + 257294336ULL);
    ushort_t* w1t   = (ushort_t*)(ws + 257425408ULL);
    ushort_t* w2t   = (ushort_t*)(ws + 257949696ULL);

    const int M = 100352;
    dim3 blk(256);
    // prep: bf16 weights
    convW<0><<<dim3(768),  blk, 0, stream>>>(qkv_w,  wqkvb,  768,  8);   // [768][256]
    convW<0><<<dim3(256),  blk, 0, stream>>>(proj_w, wprojb, 256,  8);   // [256][256]
    convW<1><<<dim3(1024), blk, 0, stream>>>(w1,     w1t,    1024, 8);   // -> [1024][256]
    convW<1><<<dim3(1024), blk, 0, stream>>>(w2,     w2t,    256, 10);   // -> [256][1024]
    // 1. qkv = gather(x) @ Wqkv^T + b  (128x256 tile, fused gather, NCOLS=3)
    gemmW<0, 1, 3><<<dim3(2352), dim3(512), 0, stream>>>(x, wqkvb, qkv_b, qkvb, M, 768, 256);
    // 2. windowed attention
    attn_mfma<<<dim3(16384), dim3(64), 0, stream>>>(qkvb, rpb, attnout);
    // 3. proj + LN1 + residual -> x1 bf16 (scattered to natural row order)
    projln1<<<dim3(784), dim3(512), 0, stream>>>(attnout, wprojb, proj_b, x,
                                                 gamma1, beta1, x1b);
    // 4. h = gelu(x1 @ W1^T + b1), full M in one dispatch
    gemmW<1, 0, 4><<<dim3(3136), dim3(512), 0, stream>>>(x1b, w1t, b1, hbuf, M, 1024, 256);
    // 5. out = x1 + LN2(h @ W2^T + b2), full M in one dispatch
    mlp2ln2<<<dim3(784), dim3(512), 0, stream>>>(hbuf, w2t, b2, x1b,
                                                 gamma2, beta2, outf);
}